// Round 4
// baseline (1199.224 us; speedup 1.0000x reference)
//
#include <hip/hip_runtime.h>
#include <cstdint>
#include <cstddef>

// Problem dims
#define MROWS 131072
#define KDIM  512
#define CDIM  256
#define NCODES 128
// Flag threshold (d_rel units). np-f32 grid/model distortion of gaps is
// bounded ~3.5e-5; 2e-4 gives 5x safety while flagging only ~1-5% of rows.
#define TAU 2e-4f

// ws layout (bytes):
//    0: double S12
//    8: double S3
//   16: int    count
//   64: float  cbnorm[128]      (fast-path, fp64-accurate)
//  576: float  bcb[128]
// 1088: float  cbnorm_np[128]   (numpy-f32 pairwise-SIMD emulation)
// 4096: float  Wcb[128*512]
// 266240: int  flaglist[131072]

// ---------------------------------------------------------------------------
// numpy f32 emulation helpers. All rounding explicit; no FMA contraction.
// pairwise-SIMD model (SSE2, W=4): 8 vector accumulators over a 128 block,
// lane l of acc j holds sum of v[32t+4j+l]; tree ((r0+r1)+(r2+r3))+((r4+r5)+(r6+r7));
// then npyv_sum: ((l0+l2)+(l1+l3)).
// ---------------------------------------------------------------------------
__device__ __forceinline__ float np_pairwise_sq128(const float* v) {
    float r[8][4];
#pragma unroll
    for (int j = 0; j < 8; ++j)
#pragma unroll
        for (int l = 0; l < 4; ++l) {
            const float x = v[4 * j + l];
            r[j][l] = __fmul_rn(x, x);
        }
#pragma unroll
    for (int t = 1; t < 4; ++t)
#pragma unroll
        for (int j = 0; j < 8; ++j)
#pragma unroll
            for (int l = 0; l < 4; ++l) {
                const float x = v[32 * t + 4 * j + l];
                r[j][l] = __fadd_rn(r[j][l], __fmul_rn(x, x));
            }
    float fin[4];
#pragma unroll
    for (int l = 0; l < 4; ++l) {
        const float r01 = __fadd_rn(r[0][l], r[1][l]);
        const float r23 = __fadd_rn(r[2][l], r[3][l]);
        const float r45 = __fadd_rn(r[4][l], r[5][l]);
        const float r67 = __fadd_rn(r[6][l], r[7][l]);
        fin[l] = __fadd_rn(__fadd_rn(r01, r23), __fadd_rn(r45, r67));
    }
    return __fadd_rn(__fadd_rn(fin[0], fin[2]), __fadd_rn(fin[1], fin[3]));
}

__device__ __forceinline__ float np_sumsq256(const float* v) {
    return __fadd_rn(np_pairwise_sq128(v), np_pairwise_sq128(v + 128));
}

// ---------------------------------------------------------------------------
// K0: Wcb = cb @ W (fp64), bcb, cbnorm (fast path), cbnorm_np (numpy model)
// ---------------------------------------------------------------------------
__global__ __launch_bounds__(256) void k0_precomp(
    const float* __restrict__ W, const float* __restrict__ b,
    const float* __restrict__ cb, float* __restrict__ Wcb,
    float* __restrict__ bcb, float* __restrict__ cbnorm,
    float* __restrict__ cbnorm_np)
{
    const int k = blockIdx.x;
    const int t = threadIdx.x;
    __shared__ float cbrow[CDIM];
    __shared__ double red[256];

    cbrow[t] = cb[(size_t)k * CDIM + t];
    __syncthreads();

    for (int pp = 0; pp < 2; ++pp) {
        const int p = t + pp * 256;
        double acc = 0.0;
        for (int c = 0; c < CDIM; ++c)
            acc += (double)cbrow[c] * (double)W[(size_t)c * KDIM + p];
        Wcb[(size_t)k * KDIM + p] = (float)acc;
    }

    red[t] = (double)cbrow[t] * (double)b[t];
    __syncthreads();
    for (int s = 128; s > 0; s >>= 1) {
        if (t < s) red[t] += red[t + s];
        __syncthreads();
    }
    if (t == 0) bcb[k] = (float)red[0];
    __syncthreads();

    red[t] = (double)cbrow[t] * (double)cbrow[t];
    __syncthreads();
    for (int s = 128; s > 0; s >>= 1) {
        if (t < s) red[t] += red[t + s];
        __syncthreads();
    }
    if (t == 0) {
        cbnorm[k]    = (float)red[0];
        cbnorm_np[k] = np_sumsq256(cbrow);
    }
}

// ---------------------------------------------------------------------------
// K1: fast scores GEMM s = plan @ Wcb^T, d_rel = cbnorm - 2 bcb - 2 s.
// Robust rows (top-2 gap >= TAU) are model-independent: any f32/f64 pipeline
// agrees. Tight rows get flagged for np-f32 emulation in k2.
// ---------------------------------------------------------------------------
__global__ __launch_bounds__(256) void k1_scores(
    const float* __restrict__ plan, const float* __restrict__ Wcb,
    const float* __restrict__ cbnorm, const float* __restrict__ bcb,
    const float* __restrict__ cb,
    float* __restrict__ out_zq, float* __restrict__ out_idx,
    double* __restrict__ S12, int* __restrict__ count,
    int* __restrict__ flaglist)
{
    const int m0  = blockIdx.x * 64;
    const int tid = threadIdx.x;
    const int tr  = tid & 15;
    const int tc  = tid >> 4;
    const int r0  = tr * 4;
    const int c0  = tc * 8;

    __shared__ __align__(16) float At[32][68];
    __shared__ __align__(16) float Bt[32][132];
    __shared__ __align__(16) float dmat[64][132];
    __shared__ int   idxs[64];
    __shared__ float dbest[64];

    float acc[4][8] = {};

    for (int k0 = 0; k0 < KDIM; k0 += 32) {
        for (int i = 0; i < 2; ++i) {
            const int s   = tid + i * 256;
            const int row = s >> 3;
            const int q   = s & 7;
            const float4 v = *(const float4*)(plan + (size_t)(m0 + row) * KDIM + k0 + q * 4);
            At[q * 4 + 0][row] = v.x;
            At[q * 4 + 1][row] = v.y;
            At[q * 4 + 2][row] = v.z;
            At[q * 4 + 3][row] = v.w;
        }
        for (int i = 0; i < 4; ++i) {
            const int s   = tid + i * 256;
            const int row = s >> 3;
            const int q   = s & 7;
            const float4 v = *(const float4*)(Wcb + (size_t)row * KDIM + k0 + q * 4);
            Bt[q * 4 + 0][row] = v.x;
            Bt[q * 4 + 1][row] = v.y;
            Bt[q * 4 + 2][row] = v.z;
            Bt[q * 4 + 3][row] = v.w;
        }
        __syncthreads();

        for (int kk = 0; kk < 32; ++kk) {
            const float4 a  = *(const float4*)&At[kk][r0];
            const float4 b0 = *(const float4*)&Bt[kk][c0];
            const float4 b1 = *(const float4*)&Bt[kk][c0 + 4];
            const float av[4] = {a.x, a.y, a.z, a.w};
            const float bv[8] = {b0.x, b0.y, b0.z, b0.w, b1.x, b1.y, b1.z, b1.w};
#pragma unroll
            for (int i = 0; i < 4; ++i)
#pragma unroll
                for (int j = 0; j < 8; ++j)
                    acc[i][j] += av[i] * bv[j];
        }
        __syncthreads();
    }

    float offv[8];
#pragma unroll
    for (int j = 0; j < 8; ++j)
        offv[j] = cbnorm[c0 + j] - 2.0f * bcb[c0 + j];

#pragma unroll
    for (int i = 0; i < 4; ++i)
#pragma unroll
        for (int j = 0; j < 8; ++j)
            dmat[r0 + i][c0 + j] = offv[j] - 2.0f * acc[i][j];
    __syncthreads();

    if (tid < 64) {
        const int r = tid;
        float v1 = 1e30f, v2 = 1e30f;
        int   i1 = 0;
        for (int k = 0; k < NCODES; ++k) {
            const float d = dmat[r][k];
            if (d < v1) { v2 = v1; v1 = d; i1 = k; }
            else if (d < v2) { v2 = d; }
        }
        idxs[r]  = i1;
        dbest[r] = v1;
        out_idx[m0 + r] = (float)i1;
        if (v2 - v1 < TAU) {
            const int pos = atomicAdd(count, 1);
            if (pos < MROWS) flaglist[pos] = m0 + r;
        }
    }
    __syncthreads();

    if (tid == 0) {
        double s = 0.0;
        for (int r = 0; r < 64; ++r) s += (double)dbest[r];
        atomicAdd(S12, s);
    }

    const float4* cb4  = (const float4*)cb;
    float4*       out4 = (float4*)out_zq;
#pragma unroll
    for (int i = 0; i < 16; ++i) {
        const int lin = i * 256 + tid;
        const int row = lin >> 6;
        const int f4  = lin & 63;
        out4[(size_t)(m0 + row) * 64 + f4] = cb4[(size_t)idxs[row] * 64 + f4];
    }
}

// ---------------------------------------------------------------------------
// K1b: z-norm GEMM for the loss term (loss threshold is loose; fp32+fp64 acc)
// ---------------------------------------------------------------------------
__global__ __launch_bounds__(256) void k1b_znorm(
    const float* __restrict__ plan, const float* __restrict__ W,
    const float* __restrict__ b, double* __restrict__ S3)
{
    const int m0  = blockIdx.x * 64;
    const int tid = threadIdx.x;
    const int tr  = tid & 15;
    const int tc  = tid >> 4;
    const int r0  = tr * 4;
    const int c0  = tc * 16;

    __shared__ __align__(16) float At[32][68];
    __shared__ __align__(16) float Wt[32][260];

    float acc[4][16] = {};

    for (int k0 = 0; k0 < KDIM; k0 += 32) {
        for (int i = 0; i < 2; ++i) {
            const int s   = tid + i * 256;
            const int row = s >> 3;
            const int q   = s & 7;
            const float4 v = *(const float4*)(plan + (size_t)(m0 + row) * KDIM + k0 + q * 4);
            At[q * 4 + 0][row] = v.x;
            At[q * 4 + 1][row] = v.y;
            At[q * 4 + 2][row] = v.z;
            At[q * 4 + 3][row] = v.w;
        }
        for (int i = 0; i < 8; ++i) {
            const int s   = tid + i * 256;
            const int row = s >> 3;
            const int q   = s & 7;
            const float4 v = *(const float4*)(W + (size_t)row * KDIM + k0 + q * 4);
            Wt[q * 4 + 0][row] = v.x;
            Wt[q * 4 + 1][row] = v.y;
            Wt[q * 4 + 2][row] = v.z;
            Wt[q * 4 + 3][row] = v.w;
        }
        __syncthreads();

        for (int kk = 0; kk < 32; ++kk) {
            const float4 a = *(const float4*)&At[kk][r0];
            const float av[4] = {a.x, a.y, a.z, a.w};
            float wv[16];
#pragma unroll
            for (int u = 0; u < 4; ++u) {
                const float4 w = *(const float4*)&Wt[kk][c0 + u * 4];
                wv[u * 4 + 0] = w.x; wv[u * 4 + 1] = w.y;
                wv[u * 4 + 2] = w.z; wv[u * 4 + 3] = w.w;
            }
#pragma unroll
            for (int i = 0; i < 4; ++i)
#pragma unroll
                for (int j = 0; j < 16; ++j)
                    acc[i][j] += av[i] * wv[j];
        }
        __syncthreads();
    }

    float bl[16];
#pragma unroll
    for (int j = 0; j < 16; ++j) bl[j] = b[c0 + j];

    double s = 0.0;
#pragma unroll
    for (int i = 0; i < 4; ++i)
#pragma unroll
        for (int j = 0; j < 16; ++j) {
            const float z = acc[i][j] + bl[j];
            s += (double)z * (double)z;
        }

    for (int off = 32; off > 0; off >>= 1)
        s += __shfl_down(s, off, 64);
    __shared__ double wsum[4];
    if ((tid & 63) == 0) wsum[tid >> 6] = s;
    __syncthreads();
    if (tid == 0)
        atomicAdd(S3, wsum[0] + wsum[1] + wsum[2] + wsum[3]);
}

// ---------------------------------------------------------------------------
// K2: numpy-f32 bit-emulation for flagged rows (Model A):
//  z[c]  : einsum universal-intrinsic SSE model — 4 lanes stride-4, mul+add
//          (no FMA), reduce ((s0+s2)+(s1+s3)), then one +b round.
//  znorm : numpy pairwise-SIMD sum of fl(z*z) (two 128-blocks).
//  cross : OpenBLAS sgemm model — single-accumulator in-order FMA chain.
//  d     : fl(fl(znorm + cbnorm_np) - fl(2*cross)); argmin = first min.
// ---------------------------------------------------------------------------
__global__ __launch_bounds__(256) void k2_refine_np(
    const float* __restrict__ plan, const float* __restrict__ W,
    const float* __restrict__ b, const float* __restrict__ cb,
    const float* __restrict__ cbnorm_np,
    const int* __restrict__ count, const int* __restrict__ flaglist,
    float* __restrict__ out_zq, float* __restrict__ out_idx)
{
    const int tid = threadIdx.x;
    __shared__ float prow[KDIM];
    __shared__ float zs[CDIM];
    __shared__ float dv[NCODES];
    __shared__ float znorm_s;
    __shared__ int   bestidx;

    int n = *count;
    if (n > MROWS) n = MROWS;
    for (int j = blockIdx.x; j < n; j += gridDim.x) {
        const int m = flaglist[j];

        prow[tid]       = plan[(size_t)m * KDIM + tid];
        prow[tid + 256] = plan[(size_t)m * KDIM + tid + 256];
        __syncthreads();

        // z[c] — einsum SSE 4-lane model
        {
            const int c = tid;
            const float* wr = W + (size_t)c * KDIM;
            float s0 = 0.f, s1 = 0.f, s2 = 0.f, s3 = 0.f;
            for (int t = 0; t < KDIM; t += 4) {
                s0 = __fadd_rn(s0, __fmul_rn(prow[t + 0], wr[t + 0]));
                s1 = __fadd_rn(s1, __fmul_rn(prow[t + 1], wr[t + 1]));
                s2 = __fadd_rn(s2, __fmul_rn(prow[t + 2], wr[t + 2]));
                s3 = __fadd_rn(s3, __fmul_rn(prow[t + 3], wr[t + 3]));
            }
            const float sop = __fadd_rn(__fadd_rn(s0, s2), __fadd_rn(s1, s3));
            zs[c] = __fadd_rn(sop, b[c]);
        }
        __syncthreads();

        if (tid == 0) znorm_s = np_sumsq256(zs);
        __syncthreads();

        if (tid < NCODES) {
            const int k = tid;
            const float* er = cb + (size_t)k * CDIM;
            float acc = 0.f;
            for (int c = 0; c < CDIM; ++c)
                acc = __fmaf_rn(zs[c], er[c], acc);
            dv[k] = __fsub_rn(__fadd_rn(znorm_s, cbnorm_np[k]),
                              __fmul_rn(2.0f, acc));
        }
        __syncthreads();

        if (tid == 0) {
            float bv = dv[0];
            int   bi = 0;
            for (int k = 1; k < NCODES; ++k)
                if (dv[k] < bv) { bv = dv[k]; bi = k; }   // strict <: first min
            bestidx = bi;
            out_idx[m] = (float)bi;
        }
        __syncthreads();

        if (tid < 64)
            ((float4*)out_zq)[(size_t)m * 64 + tid] =
                ((const float4*)cb)[(size_t)bestidx * 64 + tid];
        __syncthreads();
    }
}

// ---------------------------------------------------------------------------
// K3: loss = 1.25 * (S12 + S3) / (M * 256)
// ---------------------------------------------------------------------------
__global__ void k3_loss(const double* __restrict__ S12,
                        const double* __restrict__ S3,
                        float* __restrict__ out_loss)
{
    if (threadIdx.x == 0 && blockIdx.x == 0)
        *out_loss = (float)(1.25 * ((*S12) + (*S3)) / (double)((size_t)MROWS * CDIM));
}

// ---------------------------------------------------------------------------
extern "C" void kernel_launch(void* const* d_in, const int* in_sizes, int n_in,
                              void* d_out, int out_size, void* d_ws, size_t ws_size,
                              hipStream_t stream)
{
    const float* plan = (const float*)d_in[0];
    const float* W    = (const float*)d_in[1];
    const float* b    = (const float*)d_in[2];
    const float* cb   = (const float*)d_in[3];

    float* out_zq   = (float*)d_out;
    float* out_idx  = out_zq + (size_t)MROWS * CDIM;
    float* out_loss = out_zq + (size_t)MROWS * CDIM + MROWS;

    char*   ws        = (char*)d_ws;
    double* S12       = (double*)(ws + 0);
    double* S3        = (double*)(ws + 8);
    int*    count     = (int*)(ws + 16);
    float*  cbnorm    = (float*)(ws + 64);
    float*  bcb       = (float*)(ws + 576);
    float*  cbnorm_np = (float*)(ws + 1088);
    float*  Wcb       = (float*)(ws + 4096);
    int*    flaglist  = (int*)(ws + 266240);

    hipMemsetAsync(ws, 0, 64, stream);

    k0_precomp<<<NCODES, 256, 0, stream>>>(W, b, cb, Wcb, bcb, cbnorm, cbnorm_np);
    k1_scores<<<MROWS / 64, 256, 0, stream>>>(plan, Wcb, cbnorm, bcb, cb,
                                              out_zq, out_idx, S12, count, flaglist);
    k1b_znorm<<<MROWS / 64, 256, 0, stream>>>(plan, W, b, S3);
    k2_refine_np<<<2048, 256, 0, stream>>>(plan, W, b, cb, cbnorm_np,
                                           count, flaglist, out_zq, out_idx);
    k3_loss<<<1, 64, 0, stream>>>(S12, S3, out_loss);
}

// Round 5
// 918.416 us; speedup vs baseline: 1.3058x; 1.3058x over previous
//
#include <hip/hip_runtime.h>
#include <cstdint>
#include <cstddef>

#define MROWS 131072
#define KDIM  512
#define CDIM  256
#define NCODES 128
// Fast-path flag threshold (d units). np-f32 model distortion ~3.5e-5,
// bf16-split fast-path error ~3e-6; TAU=2e-4 gives >5x margin.
#define TAU 2e-4f

typedef __attribute__((ext_vector_type(8))) short short8;
typedef __attribute__((ext_vector_type(4))) float f32x4;

// ws layout (bytes):
//    0: double S12
//    8: double S3
//   16: int    count
//   64: float  cbnorm[128]
//  576: float  bcb[128]
// 1088: float  cbnorm_np[128]
// 4096: float  Wcb[128*512]              (fp32, 256 KiB)
// 266240: int  flaglist[131072]          (512 KiB)
// 790528: ushort Wcb_hi[128*512]         (128 KiB)
// 921600: ushort Wcb_lo[128*512]         (128 KiB)
// 1052672: ushort W_hi[256*512]          (256 KiB)  -> end 1314816

__device__ __forceinline__ unsigned short f2bf(float f) {
    unsigned int u = __float_as_uint(f);
    u += 0x7FFFu + ((u >> 16) & 1u);          // RNE to bf16
    return (unsigned short)(u >> 16);
}
__device__ __forceinline__ float bf2f(unsigned short h) {
    return __uint_as_float(((unsigned int)h) << 16);
}

// ---------------------------------------------------------------------------
// numpy f32 pairwise-SIMD sum-of-squares model (unchanged from passing run)
// ---------------------------------------------------------------------------
__device__ __forceinline__ float np_pairwise_sq128(const float* v) {
    float r[8][4];
#pragma unroll
    for (int j = 0; j < 8; ++j)
#pragma unroll
        for (int l = 0; l < 4; ++l) {
            const float x = v[4 * j + l];
            r[j][l] = __fmul_rn(x, x);
        }
#pragma unroll
    for (int t = 1; t < 4; ++t)
#pragma unroll
        for (int j = 0; j < 8; ++j)
#pragma unroll
            for (int l = 0; l < 4; ++l) {
                const float x = v[32 * t + 4 * j + l];
                r[j][l] = __fadd_rn(r[j][l], __fmul_rn(x, x));
            }
    float fin[4];
#pragma unroll
    for (int l = 0; l < 4; ++l) {
        const float r01 = __fadd_rn(r[0][l], r[1][l]);
        const float r23 = __fadd_rn(r[2][l], r[3][l]);
        const float r45 = __fadd_rn(r[4][l], r[5][l]);
        const float r67 = __fadd_rn(r[6][l], r[7][l]);
        fin[l] = __fadd_rn(__fadd_rn(r01, r23), __fadd_rn(r45, r67));
    }
    return __fadd_rn(__fadd_rn(fin[0], fin[2]), __fadd_rn(fin[1], fin[3]));
}
__device__ __forceinline__ float np_sumsq256(const float* v) {
    return __fadd_rn(np_pairwise_sq128(v), np_pairwise_sq128(v + 128));
}

// ---------------------------------------------------------------------------
// K0: Wcb = cb@W (fp64) + bf16 hi/lo split tables; W_hi bf16; bcb; cbnorms.
// ---------------------------------------------------------------------------
__global__ __launch_bounds__(256) void k0_precomp(
    const float* __restrict__ W, const float* __restrict__ b,
    const float* __restrict__ cb, float* __restrict__ Wcb,
    unsigned short* __restrict__ Wcb_hi, unsigned short* __restrict__ Wcb_lo,
    unsigned short* __restrict__ W_hi,
    float* __restrict__ bcb, float* __restrict__ cbnorm,
    float* __restrict__ cbnorm_np)
{
    const int k = blockIdx.x;
    const int t = threadIdx.x;
    __shared__ float cbrow[CDIM];
    __shared__ double red[256];

    // convert W rows 2k, 2k+1 to bf16
#pragma unroll
    for (int rr = 0; rr < 2; ++rr) {
        const int row = 2 * k + rr;
        for (int e = t; e < KDIM; e += 256)
            W_hi[(size_t)row * KDIM + e] = f2bf(W[(size_t)row * KDIM + e]);
    }

    cbrow[t] = cb[(size_t)k * CDIM + t];
    __syncthreads();

    for (int pp = 0; pp < 2; ++pp) {
        const int p = t + pp * 256;
        double acc = 0.0;
        for (int c = 0; c < CDIM; ++c)
            acc += (double)cbrow[c] * (double)W[(size_t)c * KDIM + p];
        const float f = (float)acc;
        Wcb[(size_t)k * KDIM + p] = f;
        const unsigned short hi = f2bf(f);
        Wcb_hi[(size_t)k * KDIM + p] = hi;
        Wcb_lo[(size_t)k * KDIM + p] = f2bf(f - bf2f(hi));
    }

    red[t] = (double)cbrow[t] * (double)b[t];
    __syncthreads();
    for (int s = 128; s > 0; s >>= 1) {
        if (t < s) red[t] += red[t + s];
        __syncthreads();
    }
    if (t == 0) bcb[k] = (float)red[0];
    __syncthreads();

    red[t] = (double)cbrow[t] * (double)cbrow[t];
    __syncthreads();
    for (int s = 128; s > 0; s >>= 1) {
        if (t < s) red[t] += red[t + s];
        __syncthreads();
    }
    if (t == 0) {
        cbnorm[k]    = (float)red[0];
        cbnorm_np[k] = np_sumsq256(cbrow);
    }
}

// ---------------------------------------------------------------------------
// K1M: scores via split-bf16 MFMA. No LDS, no syncthreads.
// Block = 256 thr (4 waves); wave owns 32 rows (2 x 16-row tiles), N=128.
// A frag: row = lane&15, k = 8*(lane>>4)+j (converted from fp32 in regs).
// B frag: col = lane&15, k = 8*(lane>>4)+j (bf16 tables from L2).
// D frag: col = lane&15, row = 4*(lane>>4)+reg  [m89-verified].
// s = ahi*bhi + alo*bhi + ahi*blo (alo*blo dropped, ~1e-6 noise).
// Epilogue: per-16-lane-group butterfly top-2 (np first-min exact).
// ---------------------------------------------------------------------------
__global__ __launch_bounds__(256) void k1m_scores(
    const float* __restrict__ plan,
    const unsigned short* __restrict__ Wcb_hi,
    const unsigned short* __restrict__ Wcb_lo,
    const float* __restrict__ cbnorm, const float* __restrict__ bcb,
    const float* __restrict__ cb,
    float* __restrict__ out_zq, float* __restrict__ out_idx,
    double* __restrict__ S12, int* __restrict__ count,
    int* __restrict__ flaglist)
{
    const int tid   = threadIdx.x;
    const int wv    = tid >> 6;
    const int lane  = tid & 63;
    const int l15   = lane & 15;
    const int kg    = lane >> 4;                 // 0..3
    const int mbase = blockIdx.x * 128 + wv * 32;

    f32x4 acc[2][8];
#pragma unroll
    for (int t = 0; t < 2; ++t)
#pragma unroll
        for (int n = 0; n < 8; ++n)
            acc[t][n] = (f32x4){0.f, 0.f, 0.f, 0.f};

    for (int k0 = 0; k0 < KDIM; k0 += 32) {
        short8 ah[2], al[2];
#pragma unroll
        for (int t = 0; t < 2; ++t) {
            const float* ap = plan + (size_t)(mbase + t * 16 + l15) * KDIM + k0 + kg * 8;
            const float4 x0 = *(const float4*)ap;
            const float4 x1 = *(const float4*)(ap + 4);
            const float av[8] = {x0.x, x0.y, x0.z, x0.w, x1.x, x1.y, x1.z, x1.w};
#pragma unroll
            for (int j = 0; j < 8; ++j) {
                const unsigned short hi = f2bf(av[j]);
                ah[t][j] = (short)hi;
                al[t][j] = (short)f2bf(av[j] - bf2f(hi));
            }
        }
#pragma unroll
        for (int n = 0; n < 8; ++n) {
            const size_t boff = ((size_t)(n * 16 + l15)) * KDIM + k0 + kg * 8;
            const short8 bh = *(const short8*)(Wcb_hi + boff);
            const short8 bl = *(const short8*)(Wcb_lo + boff);
#pragma unroll
            for (int t = 0; t < 2; ++t) {
                acc[t][n] = __builtin_amdgcn_mfma_f32_16x16x32_bf16(ah[t], bh, acc[t][n], 0, 0, 0);
                acc[t][n] = __builtin_amdgcn_mfma_f32_16x16x32_bf16(al[t], bh, acc[t][n], 0, 0, 0);
                acc[t][n] = __builtin_amdgcn_mfma_f32_16x16x32_bf16(ah[t], bl, acc[t][n], 0, 0, 0);
            }
        }
    }

    // d_k = cbnorm_k - 2*bcb_k - 2*s   (row-constant ||z||^2 omitted)
    float offc[8];
#pragma unroll
    for (int n = 0; n < 8; ++n) {
        const int c = n * 16 + l15;
        offc[n] = cbnorm[c] - 2.0f * bcb[c];
    }

    double s12loc = 0.0;
#pragma unroll
    for (int t = 0; t < 2; ++t) {
#pragma unroll
        for (int q = 0; q < 4; ++q) {
            const int row = mbase + t * 16 + kg * 4 + q;   // this group's row
            float v1 = 1e30f, v2 = 1e30f;
            int   i1 = 0;
#pragma unroll
            for (int n = 0; n < 8; ++n) {
                const float d = offc[n] - 2.0f * acc[t][n][q];
                if (d < v1) { v2 = v1; v1 = d; i1 = n * 16 + l15; }
                else if (d < v2) { v2 = d; }
            }
            // butterfly merge within 16-lane group (lex (v,idx): np first-min)
#pragma unroll
            for (int m = 1; m < 16; m <<= 1) {
                const float w1 = __shfl_xor(v1, m, 64);
                const float w2 = __shfl_xor(v2, m, 64);
                const int   j1 = __shfl_xor(i1, m, 64);
                if (w1 < v1 || (w1 == v1 && j1 < i1)) {
                    v2 = fminf(v1, w2);
                    v1 = w1; i1 = j1;
                } else {
                    v2 = fminf(v2, w1);
                }
            }
            if (l15 == 0) {
                out_idx[row] = (float)i1;
                s12loc += (double)v1;
                if (v2 - v1 < TAU) {
                    const int pos = atomicAdd(count, 1);
                    if (pos < MROWS) flaglist[pos] = row;
                }
            }
            // z_q row copy: 16 lanes x 4 float4
            const float4* cbr  = (const float4*)(cb + (size_t)i1 * CDIM);
            float4*       outr = (float4*)(out_zq + (size_t)row * CDIM);
#pragma unroll
            for (int jj = 0; jj < 4; ++jj)
                outr[l15 + 16 * jj] = cbr[l15 + 16 * jj];
        }
    }

    for (int off = 32; off > 0; off >>= 1)
        s12loc += __shfl_down(s12loc, off, 64);
    if (lane == 0) atomicAdd(S12, s12loc);
}

// ---------------------------------------------------------------------------
// K1BM: Sum||z||^2 via single-bf16 MFMA (loss term, ~1e-5 rel err).
// Wave owns 16 rows x 256 cols; no LDS.
// ---------------------------------------------------------------------------
__global__ __launch_bounds__(256) void k1bm_znorm(
    const float* __restrict__ plan,
    const unsigned short* __restrict__ W_hi,
    const float* __restrict__ b, double* __restrict__ S3)
{
    const int tid   = threadIdx.x;
    const int wv    = tid >> 6;
    const int lane  = tid & 63;
    const int l15   = lane & 15;
    const int kg    = lane >> 4;
    const int mbase = blockIdx.x * 64 + wv * 16;

    f32x4 acc[16];
#pragma unroll
    for (int n = 0; n < 16; ++n) acc[n] = (f32x4){0.f, 0.f, 0.f, 0.f};

    for (int k0 = 0; k0 < KDIM; k0 += 32) {
        const float* ap = plan + (size_t)(mbase + l15) * KDIM + k0 + kg * 8;
        const float4 x0 = *(const float4*)ap;
        const float4 x1 = *(const float4*)(ap + 4);
        const float av[8] = {x0.x, x0.y, x0.z, x0.w, x1.x, x1.y, x1.z, x1.w};
        short8 ah;
#pragma unroll
        for (int j = 0; j < 8; ++j) ah[j] = (short)f2bf(av[j]);
#pragma unroll
        for (int n = 0; n < 16; ++n) {
            const short8 bh = *(const short8*)(W_hi + ((size_t)(n * 16 + l15)) * KDIM + k0 + kg * 8);
            acc[n] = __builtin_amdgcn_mfma_f32_16x16x32_bf16(ah, bh, acc[n], 0, 0, 0);
        }
    }

    double s = 0.0;
#pragma unroll
    for (int n = 0; n < 16; ++n) {
        const float bb = b[n * 16 + l15];
#pragma unroll
        for (int q = 0; q < 4; ++q) {
            const float z = acc[n][q] + bb;
            s += (double)z * (double)z;
        }
    }
    for (int off = 32; off > 0; off >>= 1)
        s += __shfl_down(s, off, 64);
    if (lane == 0) atomicAdd(S3, s);
}

// ---------------------------------------------------------------------------
// K2: numpy-f32 bit-emulation for flagged rows (UNCHANGED — load-bearing).
// ---------------------------------------------------------------------------
__global__ __launch_bounds__(256) void k2_refine_np(
    const float* __restrict__ plan, const float* __restrict__ W,
    const float* __restrict__ b, const float* __restrict__ cb,
    const float* __restrict__ cbnorm_np,
    const int* __restrict__ count, const int* __restrict__ flaglist,
    float* __restrict__ out_zq, float* __restrict__ out_idx)
{
    const int tid = threadIdx.x;
    __shared__ float prow[KDIM];
    __shared__ float zs[CDIM];
    __shared__ float dv[NCODES];
    __shared__ float znorm_s;
    __shared__ int   bestidx;

    int n = *count;
    if (n > MROWS) n = MROWS;
    for (int j = blockIdx.x; j < n; j += gridDim.x) {
        const int m = flaglist[j];

        prow[tid]       = plan[(size_t)m * KDIM + tid];
        prow[tid + 256] = plan[(size_t)m * KDIM + tid + 256];
        __syncthreads();

        {
            const int c = tid;
            const float* wr = W + (size_t)c * KDIM;
            float s0 = 0.f, s1 = 0.f, s2 = 0.f, s3 = 0.f;
            for (int t = 0; t < KDIM; t += 4) {
                s0 = __fadd_rn(s0, __fmul_rn(prow[t + 0], wr[t + 0]));
                s1 = __fadd_rn(s1, __fmul_rn(prow[t + 1], wr[t + 1]));
                s2 = __fadd_rn(s2, __fmul_rn(prow[t + 2], wr[t + 2]));
                s3 = __fadd_rn(s3, __fmul_rn(prow[t + 3], wr[t + 3]));
            }
            const float sop = __fadd_rn(__fadd_rn(s0, s2), __fadd_rn(s1, s3));
            zs[c] = __fadd_rn(sop, b[c]);
        }
        __syncthreads();

        if (tid == 0) znorm_s = np_sumsq256(zs);
        __syncthreads();

        if (tid < NCODES) {
            const int k = tid;
            const float* er = cb + (size_t)k * CDIM;
            float acc = 0.f;
            for (int c = 0; c < CDIM; ++c)
                acc = __fmaf_rn(zs[c], er[c], acc);
            dv[k] = __fsub_rn(__fadd_rn(znorm_s, cbnorm_np[k]),
                              __fmul_rn(2.0f, acc));
        }
        __syncthreads();

        if (tid == 0) {
            float bv = dv[0];
            int   bi = 0;
            for (int k = 1; k < NCODES; ++k)
                if (dv[k] < bv) { bv = dv[k]; bi = k; }
            bestidx = bi;
            out_idx[m] = (float)bi;
        }
        __syncthreads();

        if (tid < 64)
            ((float4*)out_zq)[(size_t)m * 64 + tid] =
                ((const float4*)cb)[(size_t)bestidx * 64 + tid];
        __syncthreads();
    }
}

// ---------------------------------------------------------------------------
// K3: loss = 1.25 * (S12 + S3) / (M * 256)
// ---------------------------------------------------------------------------
__global__ void k3_loss(const double* __restrict__ S12,
                        const double* __restrict__ S3,
                        float* __restrict__ out_loss)
{
    if (threadIdx.x == 0 && blockIdx.x == 0)
        *out_loss = (float)(1.25 * ((*S12) + (*S3)) / (double)((size_t)MROWS * CDIM));
}

// ---------------------------------------------------------------------------
extern "C" void kernel_launch(void* const* d_in, const int* in_sizes, int n_in,
                              void* d_out, int out_size, void* d_ws, size_t ws_size,
                              hipStream_t stream)
{
    const float* plan = (const float*)d_in[0];
    const float* W    = (const float*)d_in[1];
    const float* b    = (const float*)d_in[2];
    const float* cb   = (const float*)d_in[3];

    float* out_zq   = (float*)d_out;
    float* out_idx  = out_zq + (size_t)MROWS * CDIM;
    float* out_loss = out_zq + (size_t)MROWS * CDIM + MROWS;

    char*           ws        = (char*)d_ws;
    double*         S12       = (double*)(ws + 0);
    double*         S3        = (double*)(ws + 8);
    int*            count     = (int*)(ws + 16);
    float*          cbnorm    = (float*)(ws + 64);
    float*          bcb       = (float*)(ws + 576);
    float*          cbnorm_np = (float*)(ws + 1088);
    float*          Wcb       = (float*)(ws + 4096);
    int*            flaglist  = (int*)(ws + 266240);
    unsigned short* Wcb_hi    = (unsigned short*)(ws + 790528);
    unsigned short* Wcb_lo    = (unsigned short*)(ws + 921600);
    unsigned short* W_hi      = (unsigned short*)(ws + 1052672);

    hipMemsetAsync(ws, 0, 64, stream);

    k0_precomp<<<NCODES, 256, 0, stream>>>(W, b, cb, Wcb, Wcb_hi, Wcb_lo, W_hi,
                                           bcb, cbnorm, cbnorm_np);
    k1m_scores<<<MROWS / 128, 256, 0, stream>>>(plan, Wcb_hi, Wcb_lo,
                                                cbnorm, bcb, cb,
                                                out_zq, out_idx, S12, count, flaglist);
    k1bm_znorm<<<MROWS / 64, 256, 0, stream>>>(plan, W_hi, b, S3);
    k2_refine_np<<<2048, 256, 0, stream>>>(plan, W, b, cb, cbnorm_np,
                                           count, flaglist, out_zq, out_idx);
    k3_loss<<<1, 64, 0, stream>>>(S12, S3, out_loss);
}